// Round 6
// baseline (510.305 us; speedup 1.0000x reference)
//
#include <hip/hip_runtime.h>
#include <hip/hip_bf16.h>

// ---------------------------------------------------------------------------
// GCN 2-layer forward on MI355X (gfx950).
//   prep: count (8-way replicated hist, XCD-contention-free) -> dinv+bsum
//         -> scan -> rowptr
//   CSR build: bucket_k (bin into 196 dst-buckets, ~1.5x write amp)
//              scatter2_k (per-bucket scatter into 64KB L2-local window)
//   L1: gemm_mfma<A=f32>(x,Wt1)->h_bf16 ; agg<out=bf16> -> a1_bf16
//   L2: gemm_mfma<A=bf16>(a1,Wt2)->h_bf16 ; agg<out=f32> -> d_out
// agg: 1 wave/node, half-wave per 256B bf16 row (uint2/lane), unroll 16/wave
//   (8 outstanding gathers per half-wave; R5 showed VALUBusy 33% + fetch at
//   the 8-XCD compulsory floor -> MLP-limited, not BW-limited).
// GEMM: MFMA 16x16x32 bf16, 128 rows/block, B fragment-major in LDS.
// ---------------------------------------------------------------------------

#define DIN 256
#define DH 128
#define BKT_SHIFT 9
#define BKT_SZ 512

typedef __attribute__((ext_vector_type(8))) short short8;
typedef __attribute__((ext_vector_type(4))) float f32x4;

__device__ __forceinline__ unsigned short f2bf(float f) {
    union { float f; unsigned int i; } c;
    c.f = f;
    unsigned int r = c.i + 0x7FFFu + ((c.i >> 16) & 1u);  // RNE
    return (unsigned short)(r >> 16);
}
__device__ __forceinline__ float bf_lo(unsigned int u) {
    union { unsigned int i; float f; } c;
    c.i = u << 16;
    return c.f;
}
__device__ __forceinline__ float bf_hi(unsigned int u) {
    union { unsigned int i; float f; } c;
    c.i = u & 0xFFFF0000u;
    return c.f;
}

// ---------------- prep ----------------
// 8 replicated histograms (blockIdx&7) -> no cross-XCD line bouncing
__global__ void count_k(const int* __restrict__ dst, int* __restrict__ cnt8,
                        int e, int n) {
    int i = blockIdx.x * 256 + threadIdx.x;
    if (i < e) atomicAdd(&cnt8[(blockIdx.x & 7) * n + dst[i]], 1);
}

// sum 8 copies -> cnt, dinv; fused per-block reduction -> bsum
__global__ __launch_bounds__(256) void dinv_bsum_k(const int* __restrict__ cnt8,
                                                   int* __restrict__ cnt,
                                                   float* __restrict__ dinv,
                                                   int* __restrict__ bsum, int n) {
    __shared__ int s[256];
    int t = threadIdx.x;
    int i = blockIdx.x * 256 + t;
    int c = 0;
    if (i < n) {
#pragma unroll
        for (int k = 0; k < 8; ++k) c += cnt8[k * n + i];
        cnt[i] = c;
        dinv[i] = 1.0f / sqrtf((float)(c + 1));
    }
    s[t] = c;
    __syncthreads();
    for (int off = 128; off > 0; off >>= 1) {
        if (t < off) s[t] += s[t + off];
        __syncthreads();
    }
    if (t == 0) bsum[blockIdx.x] = s[0];
}

__global__ void scan_bsum_k(int* __restrict__ bsum, int nb) {
    __shared__ int s[512];
    int t = threadIdx.x;
    s[t] = (t < nb) ? bsum[t] : 0;
    __syncthreads();
    for (int off = 1; off < 512; off <<= 1) {
        int x = (t >= off) ? s[t - off] : 0;
        __syncthreads();
        s[t] += x;
        __syncthreads();
    }
    if (t < nb) bsum[t] = (t == 0) ? 0 : s[t - 1];
}

__global__ void scan_write_k(const int* __restrict__ cnt, const int* __restrict__ bsum,
                             int* __restrict__ rowptr, int n) {
    __shared__ int s[256];
    int t = threadIdx.x;
    int i = blockIdx.x * 256 + t;
    int c = (i < n) ? cnt[i] : 0;
    s[t] = c;
    __syncthreads();
    for (int off = 1; off < 256; off <<= 1) {
        int x = (t >= off) ? s[t - off] : 0;
        __syncthreads();
        s[t] += x;
        __syncthreads();
    }
    int excl = s[t] - c + bsum[blockIdx.x];
    if (i < n) {
        rowptr[i] = excl;
        if (i == n - 1) rowptr[n] = excl + c;
    }
}

__global__ void init_bcur_k(const int* __restrict__ rowptr, int* __restrict__ bcur, int nbkt) {
    int b = threadIdx.x;
    if (b < nbkt) bcur[b] = rowptr[b << BKT_SHIFT];
}

// both weights: W1 [256][128] then W2 [128][128] -> Wt[n][k] bf16
__global__ void wt_all_k(const float* __restrict__ W1, const float* __restrict__ W2,
                         unsigned short* __restrict__ Wt1, unsigned short* __restrict__ Wt2) {
    int i = blockIdx.x * 256 + threadIdx.x;
    if (i < 256 * 128) {
        int k = i >> 7, n = i & 127;
        Wt1[(size_t)n * 256 + k] = f2bf(W1[i]);
    } else if (i < 256 * 128 + 128 * 128) {
        int j = i - 256 * 128;
        int k = j >> 7, n = j & 127;
        Wt2[(size_t)n * 128 + k] = f2bf(W2[j]);
    }
}

// ---------------- CSR build, phase 1: bucket binning ----------------
__global__ __launch_bounds__(256) void bucket_k(const int* __restrict__ src,
                                                const int* __restrict__ dst,
                                                const float* __restrict__ dinv,
                                                int* __restrict__ bcur,
                                                int2* __restrict__ tmp, int e, int n) {
    __shared__ int hist[256];
    __shared__ int rstart[256];
    int nbkt = (n + BKT_SZ - 1) >> BKT_SHIFT;
    int t = threadIdx.x;
    int nb = gridDim.x;
    int chunk = (e + nb - 1) / nb;
    int beg = blockIdx.x * chunk, end = min(e, beg + chunk);

    hist[t] = 0;
    __syncthreads();
    for (int i = beg + t; i < end; i += 256) atomicAdd(&hist[dst[i] >> BKT_SHIFT], 1);
    __syncthreads();
    int h = hist[t];
    if (t < nbkt && h > 0) rstart[t] = atomicAdd(&bcur[t], h);
    __syncthreads();
    hist[t] = 0;
    __syncthreads();
    for (int i = beg + t; i < end; i += 256) {
        int d = dst[i];
        int b = d >> BKT_SHIFT;
        int o = atomicAdd(&hist[b], 1);
        int s = src[i];
        float w = dinv[s] * dinv[d];
        tmp[rstart[b] + o] = make_int2(s | ((d & (BKT_SZ - 1)) << 20), __float_as_int(w));
    }
}

// ---------------- CSR build, phase 2: per-bucket scatter ----------------
__global__ __launch_bounds__(1024) void scatter2_k(const int2* __restrict__ tmp,
                                                   const int* __restrict__ rowptr,
                                                   int2* __restrict__ einfo, int n) {
    __shared__ int cur[BKT_SZ];
    int b = blockIdx.x;
    int t = threadIdx.x;
    int lo = b << BKT_SHIFT;
    int hi = min(n, lo + BKT_SZ);
    int nn = hi - lo;
    if (t < nn) cur[t] = rowptr[lo + t];
    __syncthreads();
    int beg = rowptr[lo], end = rowptr[hi];
    for (int i = beg + t; i < end; i += 1024) {
        int2 r = tmp[i];
        int dlow = (r.x >> 20) & (BKT_SZ - 1);
        int pos = atomicAdd(&cur[dlow], 1);
        einfo[pos] = make_int2(r.x & 0xFFFFF, r.y);
    }
}

// ---------------- GEMM (MFMA bf16) ----------------
template <bool A_BF16>
__global__ __launch_bounds__(256) void gemm_mfma(const void* __restrict__ Av,
                                                 const unsigned short* __restrict__ Wt,
                                                 unsigned short* __restrict__ Hb,
                                                 int M, int K) {
    __shared__ unsigned short Bt[16384];
    const int t = threadIdx.x;
    const int w = t >> 6;
    const int lane = t & 63;
    const int l15 = lane & 15;
    const int quad = lane >> 4;
    const int row0 = blockIdx.x * 128 + w * 32;

    const float* Af = (const float*)Av;
    const unsigned short* Ab = (const unsigned short*)Av;

    f32x4 acc[2][8];
#pragma unroll
    for (int rt = 0; rt < 2; ++rt)
#pragma unroll
        for (int ct = 0; ct < 8; ++ct)
#pragma unroll
            for (int j = 0; j < 4; ++j) acc[rt][ct][j] = 0.0f;

    for (int kc = 0; kc < K; kc += 128) {
        if (kc) __syncthreads();
#pragma unroll
        for (int i = 0; i < 8; ++i) {
            int fg = w * 8 + i;
            int ks = fg >> 3, ct = fg & 7;
            int nn = ct * 16 + l15;
            int gk = ks * 32 + quad * 8;
            *(short8*)&Bt[fg * 512 + lane * 8] =
                *(const short8*)(Wt + (size_t)nn * K + kc + gk);
        }
        __syncthreads();
#pragma unroll
        for (int ks = 0; ks < 4; ++ks) {
            int kk = ks * 32 + quad * 8;
            short8 af[2];
#pragma unroll
            for (int rt = 0; rt < 2; ++rt) {
                int row = row0 + rt * 16 + l15;
                if (row < M) {
                    if (A_BF16) {
                        af[rt] = *(const short8*)(Ab + (size_t)row * K + kc + kk);
                    } else {
                        const float* p = Af + (size_t)row * K + kc + kk;
                        float4 x0 = *(const float4*)p;
                        float4 x1 = *(const float4*)(p + 4);
                        af[rt][0] = (short)f2bf(x0.x);
                        af[rt][1] = (short)f2bf(x0.y);
                        af[rt][2] = (short)f2bf(x0.z);
                        af[rt][3] = (short)f2bf(x0.w);
                        af[rt][4] = (short)f2bf(x1.x);
                        af[rt][5] = (short)f2bf(x1.y);
                        af[rt][6] = (short)f2bf(x1.z);
                        af[rt][7] = (short)f2bf(x1.w);
                    }
                } else {
#pragma unroll
                    for (int j = 0; j < 8; ++j) af[rt][j] = 0;
                }
            }
#pragma unroll
            for (int ct = 0; ct < 8; ++ct) {
                short8 bfr = *(const short8*)&Bt[(ks * 8 + ct) * 512 + lane * 8];
                acc[0][ct] = __builtin_amdgcn_mfma_f32_16x16x32_bf16(af[0], bfr, acc[0][ct], 0, 0, 0);
                acc[1][ct] = __builtin_amdgcn_mfma_f32_16x16x32_bf16(af[1], bfr, acc[1][ct], 0, 0, 0);
            }
        }
    }
#pragma unroll
    for (int rt = 0; rt < 2; ++rt)
#pragma unroll
        for (int r = 0; r < 4; ++r) {
            int row = row0 + rt * 16 + quad * 4 + r;
            if (row < M) {
                unsigned short* o = Hb + (size_t)row * 128 + l15;
#pragma unroll
                for (int ct = 0; ct < 8; ++ct) o[ct * 16] = f2bf(acc[rt][ct][r]);
            }
        }
}

// ---------------- aggregation ----------------
// 1 wave/node; half-wave (32 lanes) covers a 256B bf16 row via uint2/lane.
// halves process even/odd edges; tiers: 16/wave, 8/wave, 2/wave.
template <bool OUT_BF16>
__global__ __launch_bounds__(256) void agg_k(const unsigned short* __restrict__ Hb,
                                             const int* __restrict__ rowptr,
                                             const int2* __restrict__ einfo,
                                             const float* __restrict__ dinv,
                                             const float* __restrict__ bias,
                                             void* __restrict__ out, int n) {
    int v = blockIdx.x * 4 + (threadIdx.x >> 6);
    int lane = threadIdx.x & 63;
    if (v >= n) return;
    int l = lane & 31, half = lane >> 5;
    const uint2* __restrict__ H = (const uint2*)Hb;  // row = 32 x uint2
    float a0 = 0.f, a1 = 0.f, a2 = 0.f, a3 = 0.f;
    if (half == 0) {
        float dv = dinv[v];
        float self = dv * dv;
        uint2 hv = H[(size_t)v * 32 + l];
        a0 = self * bf_lo(hv.x); a1 = self * bf_hi(hv.x);
        a2 = self * bf_lo(hv.y); a3 = self * bf_hi(hv.y);
    }
    int end = rowptr[v + 1];
    int i = rowptr[v] + half;
    // tier 1: 8 edges per half-wave in flight
    for (; i + 14 < end; i += 16) {
        int2 e0 = einfo[i],      e1 = einfo[i + 2],  e2 = einfo[i + 4],  e3 = einfo[i + 6];
        int2 e4 = einfo[i + 8],  e5 = einfo[i + 10], e6 = einfo[i + 12], e7 = einfo[i + 14];
        uint2 v0 = H[(size_t)e0.x * 32 + l];
        uint2 v1 = H[(size_t)e1.x * 32 + l];
        uint2 v2 = H[(size_t)e2.x * 32 + l];
        uint2 v3 = H[(size_t)e3.x * 32 + l];
        uint2 v4 = H[(size_t)e4.x * 32 + l];
        uint2 v5 = H[(size_t)e5.x * 32 + l];
        uint2 v6 = H[(size_t)e6.x * 32 + l];
        uint2 v7 = H[(size_t)e7.x * 32 + l];
        float w0 = __int_as_float(e0.y), w1 = __int_as_float(e1.y);
        float w2 = __int_as_float(e2.y), w3 = __int_as_float(e3.y);
        float w4 = __int_as_float(e4.y), w5 = __int_as_float(e5.y);
        float w6 = __int_as_float(e6.y), w7 = __int_as_float(e7.y);
        a0 = fmaf(w0, bf_lo(v0.x), a0); a1 = fmaf(w0, bf_hi(v0.x), a1);
        a2 = fmaf(w0, bf_lo(v0.y), a2); a3 = fmaf(w0, bf_hi(v0.y), a3);
        a0 = fmaf(w1, bf_lo(v1.x), a0); a1 = fmaf(w1, bf_hi(v1.x), a1);
        a2 = fmaf(w1, bf_lo(v1.y), a2); a3 = fmaf(w1, bf_hi(v1.y), a3);
        a0 = fmaf(w2, bf_lo(v2.x), a0); a1 = fmaf(w2, bf_hi(v2.x), a1);
        a2 = fmaf(w2, bf_lo(v2.y), a2); a3 = fmaf(w2, bf_hi(v2.y), a3);
        a0 = fmaf(w3, bf_lo(v3.x), a0); a1 = fmaf(w3, bf_hi(v3.x), a1);
        a2 = fmaf(w3, bf_lo(v3.y), a2); a3 = fmaf(w3, bf_hi(v3.y), a3);
        a0 = fmaf(w4, bf_lo(v4.x), a0); a1 = fmaf(w4, bf_hi(v4.x), a1);
        a2 = fmaf(w4, bf_lo(v4.y), a2); a3 = fmaf(w4, bf_hi(v4.y), a3);
        a0 = fmaf(w5, bf_lo(v5.x), a0); a1 = fmaf(w5, bf_hi(v5.x), a1);
        a2 = fmaf(w5, bf_lo(v5.y), a2); a3 = fmaf(w5, bf_hi(v5.y), a3);
        a0 = fmaf(w6, bf_lo(v6.x), a0); a1 = fmaf(w6, bf_hi(v6.x), a1);
        a2 = fmaf(w6, bf_lo(v6.y), a2); a3 = fmaf(w6, bf_hi(v6.y), a3);
        a0 = fmaf(w7, bf_lo(v7.x), a0); a1 = fmaf(w7, bf_hi(v7.x), a1);
        a2 = fmaf(w7, bf_lo(v7.y), a2); a3 = fmaf(w7, bf_hi(v7.y), a3);
    }
    // tier 2: 4 edges per half-wave
    for (; i + 6 < end; i += 8) {
        int2 e0 = einfo[i], e1 = einfo[i + 2], e2 = einfo[i + 4], e3 = einfo[i + 6];
        uint2 v0 = H[(size_t)e0.x * 32 + l];
        uint2 v1 = H[(size_t)e1.x * 32 + l];
        uint2 v2 = H[(size_t)e2.x * 32 + l];
        uint2 v3 = H[(size_t)e3.x * 32 + l];
        float w0 = __int_as_float(e0.y), w1 = __int_as_float(e1.y);
        float w2 = __int_as_float(e2.y), w3 = __int_as_float(e3.y);
        a0 = fmaf(w0, bf_lo(v0.x), a0); a1 = fmaf(w0, bf_hi(v0.x), a1);
        a2 = fmaf(w0, bf_lo(v0.y), a2); a3 = fmaf(w0, bf_hi(v0.y), a3);
        a0 = fmaf(w1, bf_lo(v1.x), a0); a1 = fmaf(w1, bf_hi(v1.x), a1);
        a2 = fmaf(w1, bf_lo(v1.y), a2); a3 = fmaf(w1, bf_hi(v1.y), a3);
        a0 = fmaf(w2, bf_lo(v2.x), a0); a1 = fmaf(w2, bf_hi(v2.x), a1);
        a2 = fmaf(w2, bf_lo(v2.y), a2); a3 = fmaf(w2, bf_hi(v2.y), a3);
        a0 = fmaf(w3, bf_lo(v3.x), a0); a1 = fmaf(w3, bf_hi(v3.x), a1);
        a2 = fmaf(w3, bf_lo(v3.y), a2); a3 = fmaf(w3, bf_hi(v3.y), a3);
    }
    for (; i < end; i += 2) {
        int2 e = einfo[i];
        uint2 vv = H[(size_t)e.x * 32 + l];
        float w = __int_as_float(e.y);
        a0 = fmaf(w, bf_lo(vv.x), a0); a1 = fmaf(w, bf_hi(vv.x), a1);
        a2 = fmaf(w, bf_lo(vv.y), a2); a3 = fmaf(w, bf_hi(vv.y), a3);
    }
    a0 += __shfl_xor(a0, 32);
    a1 += __shfl_xor(a1, 32);
    a2 += __shfl_xor(a2, 32);
    a3 += __shfl_xor(a3, 32);
    if (half == 0) {
        float4 bb = ((const float4*)bias)[l];
        float o0 = fmaxf(a0 + bb.x, 0.f);
        float o1 = fmaxf(a1 + bb.y, 0.f);
        float o2 = fmaxf(a2 + bb.z, 0.f);
        float o3 = fmaxf(a3 + bb.w, 0.f);
        if (OUT_BF16) {
            unsigned int p0 = (unsigned int)f2bf(o0) | ((unsigned int)f2bf(o1) << 16);
            unsigned int p1 = (unsigned int)f2bf(o2) | ((unsigned int)f2bf(o3) << 16);
            ((uint2*)out)[(size_t)v * 32 + l] = make_uint2(p0, p1);
        } else {
            ((float4*)out)[(size_t)v * 32 + l] = make_float4(o0, o1, o2, o3);
        }
    }
}

static inline size_t align_up(size_t x, size_t a) { return (x + a - 1) & ~(a - 1); }

extern "C" void kernel_launch(void* const* d_in, const int* in_sizes, int n_in,
                              void* d_out, int out_size, void* d_ws, size_t ws_size,
                              hipStream_t stream) {
    const float* x  = (const float*)d_in[0];
    const int*   ei = (const int*)d_in[1];
    const float* W1 = (const float*)d_in[2];
    const float* b1 = (const float*)d_in[3];
    const float* W2 = (const float*)d_in[4];
    const float* b2 = (const float*)d_in[5];

    const int N = in_sizes[0] / DIN;   // 100000
    const int E = in_sizes[1] / 2;     // 1600000
    const int* src = ei;
    const int* dst = ei + E;
    const int NBKT = (N + BKT_SZ - 1) >> BKT_SHIFT;  // 196

    // workspace partition
    char* base = (char*)d_ws;
    size_t off = 0;
    int* cnt8 = (int*)(base + off);         off = align_up(off + (size_t)8 * N * 4, 256);
    int* cnt = (int*)(base + off);          off = align_up(off + (size_t)N * 4, 256);
    int* rowptr = (int*)(base + off);       off = align_up(off + (size_t)(N + 1) * 4, 256);
    float* dinv = (float*)(base + off);     off = align_up(off + (size_t)N * 4, 256);
    int* bsum = (int*)(base + off);         off = align_up(off + 512 * 4, 256);
    int* bcur = (int*)(base + off);         off = align_up(off + 256 * 4, 256);
    int2* tmp = (int2*)(base + off);        off = align_up(off + (size_t)E * 8, 256);
    int2* einfo = (int2*)(base + off);      off = align_up(off + (size_t)E * 8, 256);
    unsigned short* Wt1 = (unsigned short*)(base + off); off = align_up(off + (size_t)128 * 256 * 2, 256);
    unsigned short* Wt2 = (unsigned short*)(base + off); off = align_up(off + (size_t)128 * 128 * 2, 256);
    unsigned short* hb  = (unsigned short*)(base + off); off = align_up(off + (size_t)N * 128 * 2, 256);
    unsigned short* a1b = (unsigned short*)(base + off); off = align_up(off + (size_t)N * 128 * 2, 256);

    float* out = (float*)d_out;
    const int NB = (N + 255) / 256;

    hipMemsetAsync(cnt8, 0, (size_t)8 * N * sizeof(int), stream);
    count_k<<<(E + 255) / 256, 256, 0, stream>>>(dst, cnt8, E, N);
    dinv_bsum_k<<<NB, 256, 0, stream>>>(cnt8, cnt, dinv, bsum, N);
    scan_bsum_k<<<1, 512, 0, stream>>>(bsum, NB);
    scan_write_k<<<NB, 256, 0, stream>>>(cnt, bsum, rowptr, N);
    init_bcur_k<<<1, 256, 0, stream>>>(rowptr, bcur, NBKT);
    wt_all_k<<<(256 * 128 + 128 * 128 + 255) / 256, 256, 0, stream>>>(W1, W2, Wt1, Wt2);

    // CSR build
    bucket_k<<<512, 256, 0, stream>>>(src, dst, dinv, bcur, tmp, E, N);
    scatter2_k<<<NBKT, 1024, 0, stream>>>(tmp, rowptr, einfo, N);

    const int GB = (N + 127) / 128;
    // layer 1
    gemm_mfma<false><<<GB, 256, 0, stream>>>(x, Wt1, hb, N, DIN);
    agg_k<true><<<(N + 3) / 4, 256, 0, stream>>>(hb, rowptr, einfo, dinv, b1, a1b, N);
    // layer 2
    gemm_mfma<true><<<GB, 256, 0, stream>>>(a1b, Wt2, hb, N, DH);
    agg_k<false><<<(N + 3) / 4, 256, 0, stream>>>(hb, rowptr, einfo, dinv, b2, out, N);
}

// Round 8
// 429.425 us; speedup vs baseline: 1.1883x; 1.1883x over previous
//
#include <hip/hip_runtime.h>
#include <hip/hip_bf16.h>

// ---------------------------------------------------------------------------
// GCN 2-layer forward on MI355X (gfx950).
// Algebra: store g[s]=dinv[s]*h[s] (scaled in GEMM epilogue) so
//   out[v] = relu(dinv[v]*(sum_{s in N(v)} g[s] + g[v]) + b)
// -> CSR needs NO weights (einfo = 4B src) and NO dinv -> no count/scan chain.
// Pipeline (7 launches):
//   memset(bcnt) ; prep_k{bucket blocks + wt blocks} ; scan196 ; scatter2
//   gemm1(x,Wt1,dinv)->g1 ; agg1->a1 ; gemm2(a1,Wt2,dinv)->g2 ; agg2->out
// bucket: 512 blocks bin edges into 196 fixed-cap dst-buckets (LDS hist +
//   block run-reservation, ~64B runs). scatter2: 1 block/bucket; LDS hist
//   (=deg -> dinv), LDS scan (-> rowptr), scatter 4B recs into the bucket's
//   L2-local CSR window (R4 lesson: window must be single-CU/XCD-owned).
// agg: 1 wave/node, half-wave per 256B bf16 row (uint2/lane), 4 outstanding
//   gathers/half (R6 lesson: deeper MLP hurts occupancy, no gain; fill-path
//   at 8-XCD compulsory floor ~195MB is the ceiling).
// GEMM: MFMA 16x16x32 bf16, 128 rows/block, B fragment-major in LDS
//   (stride-1 b128, conflict-free), epilogue scales by dinv[row].
// ---------------------------------------------------------------------------

#define DIN 256
#define DH 128
#define BKT_SHIFT 9
#define BKT_SZ 512
#define NBKT_MAX 256
#define CAP 10240

typedef __attribute__((ext_vector_type(8))) short short8;
typedef __attribute__((ext_vector_type(4))) float f32x4;
typedef __attribute__((ext_vector_type(2))) unsigned int uint2e;

__device__ __forceinline__ unsigned short f2bf(float f) {
    union { float f; unsigned int i; } c;
    c.f = f;
    unsigned int r = c.i + 0x7FFFu + ((c.i >> 16) & 1u);  // RNE
    return (unsigned short)(r >> 16);
}
__device__ __forceinline__ float bf_lo(unsigned int u) {
    union { unsigned int i; float f; } c;
    c.i = u << 16;
    return c.f;
}
__device__ __forceinline__ float bf_hi(unsigned int u) {
    union { unsigned int i; float f; } c;
    c.i = u & 0xFFFF0000u;
    return c.f;
}

// ---------------- prep: bucket binning (blocks 0..NBB) + weight cvt ----------
// record: src | (dlow9 << 20)  (src < 2^17)
__global__ __launch_bounds__(256) void prep_k(const int* __restrict__ src,
                                              const int* __restrict__ dst,
                                              int* __restrict__ bcnt,
                                              int* __restrict__ tmp, int e, int n,
                                              int NBB,
                                              const float* __restrict__ W1,
                                              const float* __restrict__ W2,
                                              unsigned short* __restrict__ Wt1,
                                              unsigned short* __restrict__ Wt2) {
    int bx = blockIdx.x;
    int t = threadIdx.x;
    if (bx >= NBB) {
        // weight conversion: W1 [256][128], W2 [128][128] -> Wt[n][k] bf16
        int i = (bx - NBB) * 256 + t;
        if (i < 256 * 128) {
            int k = i >> 7, nn = i & 127;
            Wt1[(size_t)nn * 256 + k] = f2bf(W1[i]);
        } else if (i < 256 * 128 + 128 * 128) {
            int j = i - 256 * 128;
            int k = j >> 7, nn = j & 127;
            Wt2[(size_t)nn * 128 + k] = f2bf(W2[j]);
        }
        return;
    }
    __shared__ int hist[NBKT_MAX];
    __shared__ int rstart[NBKT_MAX];
    int nbkt = (n + BKT_SZ - 1) >> BKT_SHIFT;  // 196
    int chunk = (e + NBB - 1) / NBB;
    int beg = bx * chunk, end = min(e, beg + chunk);

    hist[t] = 0;
    __syncthreads();
    for (int i = beg + t; i < end; i += 256) atomicAdd(&hist[dst[i] >> BKT_SHIFT], 1);
    __syncthreads();
    int h = hist[t];
    if (t < nbkt && h > 0) rstart[t] = atomicAdd(&bcnt[t], h);
    __syncthreads();
    hist[t] = 0;
    __syncthreads();
    for (int i = beg + t; i < end; i += 256) {
        int d = dst[i];
        int b = d >> BKT_SHIFT;
        int o = atomicAdd(&hist[b], 1);
        tmp[(size_t)b * CAP + rstart[b] + o] = src[i] | ((d & (BKT_SZ - 1)) << 20);
    }
}

// exclusive scan of bcnt[0..nbkt) -> base[0..nbkt]; rowptr[n] = E
__global__ void scan196_k(const int* __restrict__ bcnt, int* __restrict__ base,
                          int* __restrict__ rowptr, int nbkt, int n) {
    __shared__ int s[256];
    int t = threadIdx.x;
    s[t] = (t < nbkt) ? bcnt[t] : 0;
    __syncthreads();
    for (int off = 1; off < 256; off <<= 1) {
        int x = (t >= off) ? s[t - off] : 0;
        __syncthreads();
        s[t] += x;
        __syncthreads();
    }
    base[t] = (t == 0) ? 0 : s[t - 1];  // exclusive
    if (t == nbkt - 1) {
        base[nbkt] = s[t];
        rowptr[n] = s[t];  // == E
    }
}

// ---------------- per-bucket: deg->dinv, local scan->rowptr, scatter --------
__global__ __launch_bounds__(1024) void scatter2_k(const int* __restrict__ tmp,
                                                   const int* __restrict__ bcnt,
                                                   const int* __restrict__ base,
                                                   float* __restrict__ dinv,
                                                   int* __restrict__ rowptr,
                                                   int* __restrict__ einfo, int n) {
    __shared__ int hist[BKT_SZ];
    __shared__ int scn[BKT_SZ];
    __shared__ int cur[BKT_SZ];
    int b = blockIdx.x;
    int t = threadIdx.x;
    int lo = b << BKT_SHIFT;
    int nn = min(n - lo, BKT_SZ);
    int cnt = bcnt[b];
    int bas = base[b];
    const int* rec = tmp + (size_t)b * CAP;
    if (t < BKT_SZ) hist[t] = 0;
    __syncthreads();
    for (int i = t; i < cnt; i += 1024) atomicAdd(&hist[(rec[i] >> 20) & (BKT_SZ - 1)], 1);
    __syncthreads();
    if (t < BKT_SZ) scn[t] = hist[t];
    __syncthreads();
    for (int off = 1; off < BKT_SZ; off <<= 1) {
        int x = 0;
        if (t < BKT_SZ && t >= off) x = scn[t - off];
        __syncthreads();
        if (t < BKT_SZ) scn[t] += x;
        __syncthreads();
    }
    if (t < nn) {
        int excl = bas + scn[t] - hist[t];
        dinv[lo + t] = 1.0f / sqrtf((float)(hist[t] + 1));
        rowptr[lo + t] = excl;
        cur[t] = excl;
    }
    __syncthreads();
    for (int i = t; i < cnt; i += 1024) {
        int r = rec[i];
        int dlow = (r >> 20) & (BKT_SZ - 1);
        int pos = atomicAdd(&cur[dlow], 1);
        einfo[pos] = r & 0xFFFFF;
    }
}

// ---------------- GEMM (MFMA bf16), epilogue scales by dinv[row] ------------
// G[M,128] = dinv[row] * (A[M,K] @ Wt^T), bf16 out. Wt is [128][K] bf16.
template <bool A_BF16>
__global__ __launch_bounds__(256) void gemm_mfma(const void* __restrict__ Av,
                                                 const unsigned short* __restrict__ Wt,
                                                 const float* __restrict__ dinv,
                                                 unsigned short* __restrict__ Hb,
                                                 int M, int K) {
    __shared__ unsigned short Bt[16384];
    const int t = threadIdx.x;
    const int w = t >> 6;
    const int lane = t & 63;
    const int l15 = lane & 15;
    const int quad = lane >> 4;
    const int row0 = blockIdx.x * 128 + w * 32;

    const float* Af = (const float*)Av;
    const unsigned short* Ab = (const unsigned short*)Av;

    f32x4 acc[2][8];
#pragma unroll
    for (int rt = 0; rt < 2; ++rt)
#pragma unroll
        for (int ct = 0; ct < 8; ++ct)
#pragma unroll
            for (int j = 0; j < 4; ++j) acc[rt][ct][j] = 0.0f;

    for (int kc = 0; kc < K; kc += 128) {
        if (kc) __syncthreads();
#pragma unroll
        for (int i = 0; i < 8; ++i) {
            int fg = w * 8 + i;
            int ks = fg >> 3, ct = fg & 7;
            int nn = ct * 16 + l15;
            int gk = ks * 32 + quad * 8;
            *(short8*)&Bt[fg * 512 + lane * 8] =
                *(const short8*)(Wt + (size_t)nn * K + kc + gk);
        }
        __syncthreads();
#pragma unroll
        for (int ks = 0; ks < 4; ++ks) {
            int kk = ks * 32 + quad * 8;
            short8 af[2];
#pragma unroll
            for (int rt = 0; rt < 2; ++rt) {
                int row = row0 + rt * 16 + l15;
                if (row < M) {
                    if (A_BF16) {
                        af[rt] = *(const short8*)(Ab + (size_t)row * K + kc + kk);
                    } else {
                        const float* p = Af + (size_t)row * K + kc + kk;
                        float4 x0 = *(const float4*)p;
                        float4 x1 = *(const float4*)(p + 4);
                        af[rt][0] = (short)f2bf(x0.x);
                        af[rt][1] = (short)f2bf(x0.y);
                        af[rt][2] = (short)f2bf(x0.z);
                        af[rt][3] = (short)f2bf(x0.w);
                        af[rt][4] = (short)f2bf(x1.x);
                        af[rt][5] = (short)f2bf(x1.y);
                        af[rt][6] = (short)f2bf(x1.z);
                        af[rt][7] = (short)f2bf(x1.w);
                    }
                } else {
#pragma unroll
                    for (int j = 0; j < 8; ++j) af[rt][j] = 0;
                }
            }
#pragma unroll
            for (int ct = 0; ct < 8; ++ct) {
                short8 bfr = *(const short8*)&Bt[(ks * 8 + ct) * 512 + lane * 8];
                acc[0][ct] = __builtin_amdgcn_mfma_f32_16x16x32_bf16(af[0], bfr, acc[0][ct], 0, 0, 0);
                acc[1][ct] = __builtin_amdgcn_mfma_f32_16x16x32_bf16(af[1], bfr, acc[1][ct], 0, 0, 0);
            }
        }
    }
#pragma unroll
    for (int rt = 0; rt < 2; ++rt)
#pragma unroll
        for (int r = 0; r < 4; ++r) {
            int row = row0 + rt * 16 + quad * 4 + r;
            if (row < M) {
                float dv = dinv[row];
                unsigned short* o = Hb + (size_t)row * 128 + l15;
#pragma unroll
                for (int ct = 0; ct < 8; ++ct) o[ct * 16] = f2bf(dv * acc[rt][ct][r]);
            }
        }
}

// ---------------- aggregation ----------------
// out[v] = relu(dinv[v]*(sum g[s] + g[v]) + b). 1 wave/node; half-wave per
// 256B bf16 row (uint2/lane); halves take even/odd edges; 4 gathers in flight.
template <bool OUT_BF16>
__global__ __launch_bounds__(256) void agg_k(const unsigned short* __restrict__ Hb,
                                             const int* __restrict__ rowptr,
                                             const int* __restrict__ einfo,
                                             const float* __restrict__ dinv,
                                             const float* __restrict__ bias,
                                             void* __restrict__ out, int n) {
    int v = blockIdx.x * 4 + (threadIdx.x >> 6);
    int lane = threadIdx.x & 63;
    if (v >= n) return;
    int l = lane & 31, half = lane >> 5;
    const uint2* __restrict__ H = (const uint2*)Hb;  // row = 32 x uint2
    float a0 = 0.f, a1 = 0.f, a2 = 0.f, a3 = 0.f;
    if (half == 0) {
        uint2 hv = H[(size_t)v * 32 + l];  // self: + g[v]
        a0 = bf_lo(hv.x); a1 = bf_hi(hv.x);
        a2 = bf_lo(hv.y); a3 = bf_hi(hv.y);
    }
    int end = rowptr[v + 1];
    int i = rowptr[v] + half;
    for (; i + 6 < end; i += 8) {
        int s0 = __builtin_nontemporal_load(&einfo[i]);
        int s1 = __builtin_nontemporal_load(&einfo[i + 2]);
        int s2 = __builtin_nontemporal_load(&einfo[i + 4]);
        int s3 = __builtin_nontemporal_load(&einfo[i + 6]);
        uint2 v0 = H[(size_t)s0 * 32 + l];
        uint2 v1 = H[(size_t)s1 * 32 + l];
        uint2 v2 = H[(size_t)s2 * 32 + l];
        uint2 v3 = H[(size_t)s3 * 32 + l];
        a0 += bf_lo(v0.x); a1 += bf_hi(v0.x); a2 += bf_lo(v0.y); a3 += bf_hi(v0.y);
        a0 += bf_lo(v1.x); a1 += bf_hi(v1.x); a2 += bf_lo(v1.y); a3 += bf_hi(v1.y);
        a0 += bf_lo(v2.x); a1 += bf_hi(v2.x); a2 += bf_lo(v2.y); a3 += bf_hi(v2.y);
        a0 += bf_lo(v3.x); a1 += bf_hi(v3.x); a2 += bf_lo(v3.y); a3 += bf_hi(v3.y);
    }
    for (; i < end; i += 2) {
        int s = __builtin_nontemporal_load(&einfo[i]);
        uint2 vv = H[(size_t)s * 32 + l];
        a0 += bf_lo(vv.x); a1 += bf_hi(vv.x); a2 += bf_lo(vv.y); a3 += bf_hi(vv.y);
    }
    a0 += __shfl_xor(a0, 32);
    a1 += __shfl_xor(a1, 32);
    a2 += __shfl_xor(a2, 32);
    a3 += __shfl_xor(a3, 32);
    if (half == 0) {
        float dv = dinv[v];
        float4 bb = ((const float4*)bias)[l];
        float o0 = fmaxf(fmaf(dv, a0, bb.x), 0.f);
        float o1 = fmaxf(fmaf(dv, a1, bb.y), 0.f);
        float o2 = fmaxf(fmaf(dv, a2, bb.z), 0.f);
        float o3 = fmaxf(fmaf(dv, a3, bb.w), 0.f);
        if (OUT_BF16) {
            uint2e p;
            p.x = (unsigned int)f2bf(o0) | ((unsigned int)f2bf(o1) << 16);
            p.y = (unsigned int)f2bf(o2) | ((unsigned int)f2bf(o3) << 16);
            __builtin_nontemporal_store(p, (uint2e*)out + (size_t)v * 32 + l);
        } else {
            f32x4 o = {o0, o1, o2, o3};
            __builtin_nontemporal_store(o, (f32x4*)out + (size_t)v * 32 + l);
        }
    }
}

static inline size_t align_up(size_t x, size_t a) { return (x + a - 1) & ~(a - 1); }

extern "C" void kernel_launch(void* const* d_in, const int* in_sizes, int n_in,
                              void* d_out, int out_size, void* d_ws, size_t ws_size,
                              hipStream_t stream) {
    const float* x  = (const float*)d_in[0];
    const int*   ei = (const int*)d_in[1];
    const float* W1 = (const float*)d_in[2];
    const float* b1 = (const float*)d_in[3];
    const float* W2 = (const float*)d_in[4];
    const float* b2 = (const float*)d_in[5];

    const int N = in_sizes[0] / DIN;   // 100000
    const int E = in_sizes[1] / 2;     // 1600000
    const int* src = ei;
    const int* dst = ei + E;
    const int NBKT = (N + BKT_SZ - 1) >> BKT_SHIFT;  // 196

    // workspace partition
    char* base_p = (char*)d_ws;
    size_t off = 0;
    int* bcnt = (int*)(base_p + off);       off = align_up(off + 256 * 4, 256);
    int* bbase = (int*)(base_p + off);      off = align_up(off + 257 * 4, 256);
    int* rowptr = (int*)(base_p + off);     off = align_up(off + (size_t)(N + 1) * 4, 256);
    float* dinv = (float*)(base_p + off);   off = align_up(off + (size_t)N * 4, 256);
    int* tmp = (int*)(base_p + off);        off = align_up(off + (size_t)NBKT * CAP * 4, 256);
    int* einfo = (int*)(base_p + off);      off = align_up(off + (size_t)E * 4, 256);
    unsigned short* Wt1 = (unsigned short*)(base_p + off); off = align_up(off + (size_t)128 * 256 * 2, 256);
    unsigned short* Wt2 = (unsigned short*)(base_p + off); off = align_up(off + (size_t)128 * 128 * 2, 256);
    unsigned short* hb  = (unsigned short*)(base_p + off); off = align_up(off + (size_t)N * 128 * 2, 256);
    unsigned short* a1b = (unsigned short*)(base_p + off); off = align_up(off + (size_t)N * 128 * 2, 256);

    float* out = (float*)d_out;

    const int NBB = 512;                       // bucket blocks
    const int WTB = (256 * 128 + 128 * 128 + 255) / 256;  // 192 weight blocks

    hipMemsetAsync(bcnt, 0, 256 * sizeof(int), stream);
    prep_k<<<NBB + WTB, 256, 0, stream>>>(src, dst, bcnt, tmp, E, N, NBB, W1, W2, Wt1, Wt2);
    scan196_k<<<1, 256, 0, stream>>>(bcnt, bbase, rowptr, NBKT, N);
    scatter2_k<<<NBKT, 1024, 0, stream>>>(tmp, bcnt, bbase, dinv, rowptr, einfo, N);

    const int GB = (N + 127) / 128;
    // layer 1
    gemm_mfma<false><<<GB, 256, 0, stream>>>(x, Wt1, dinv, hb, N, DIN);
    agg_k<true><<<(N + 3) / 4, 256, 0, stream>>>(hb, rowptr, einfo, dinv, b1, a1b, N);
    // layer 2
    gemm_mfma<true><<<GB, 256, 0, stream>>>(a1b, Wt2, dinv, hb, N, DH);
    agg_k<false><<<(N + 3) / 4, 256, 0, stream>>>(hb, rowptr, einfo, dinv, b2, out, N);
}